// Round 6
// baseline (7156.944 us; speedup 1.0000x reference)
//
#include <hip/hip_runtime.h>
#include <math.h>

// Problem constants (fixed by setup_inputs)
#define Bn   4
#define Nn   16384
#define CINn 32
#define DIMn 256
#define Sn   2048
#define KNEI 16
#define BNEPS 1e-5f
#define MROWS (Bn * Nn)   // 65536
#define SROWS (Bn * Sn)   // 8192

// FPS decomposition
#define GFPS 8                       // workgroups per batch
#define TFPS 256                     // threads per FPS workgroup
#define PPT  (Nn / (GFPS * TFPS))    // 8 points per thread

// ---------------------------------------------------------------------------
// flag reset (must be a separate kernel: no WG may reset while others poll)
// ---------------------------------------------------------------------------
__global__ __launch_bounds__(64) void fps_zero_kernel(unsigned* __restrict__ flags)
{
    if (threadIdx.x < Bn * GFPS) flags[threadIdx.x] = 0u;
}

// ---------------------------------------------------------------------------
// K1: furthest point sampling, v6 (multi-CU with device-scope sync).
// Rounds 1-5 lesson: one CU per batch caps FPS at ~3.6ms (VALU issue floor +
// L2 delivery + serial reduce; FETCH_SIZE is KB -- everything is L2-resident,
// there never was an HBM problem). So split each batch across 8 WGs (8 CUs):
// 2048 pts/WG = 24KB (L1-resident), update cost /8.
// Cross-WG protocol per iteration (race-free by construction):
//   - WG publishes its local best key to kbuf[i&1][wg] (relaxed, agent scope)
//     then release-stores flag[wg] = i+1.
//   - All WGs acquire-poll all 8 flags >= i+1, read the 8 keys, reduce
//     locally (symmetric -- no broadcast hop).
//   - Depth-2 ping-pong is safe: a writer reaches iter i+2 only after all
//     peers published i+1, which implies they finished READING iter i.
//   - flags monotone within a launch; zeroed by fps_zero_kernel each launch
//     (graph-replay safe, no cross-call state).
// Numerics identical to reference: contract OFF, d=(dx*dx+dy*dy)+dz*dz,
// running fminf, argmax tie -> lowest ORIGINAL index via key = dist<<32 | ~n.
// ---------------------------------------------------------------------------
__global__ __launch_bounds__(TFPS) void fps_kernel(const float* __restrict__ xyz,
                                                   int* __restrict__ fidx,
                                                   float* __restrict__ newxyz,
                                                   unsigned* __restrict__ flags,
                                                   unsigned long long* __restrict__ kbuf)
{
#pragma clang fp contract(off)
    __shared__ unsigned long long s_wk[TFPS / 64];
    __shared__ unsigned long long s_win;
    const int wg = blockIdx.x;
    const int b = wg >> 3;
    const int g = wg & 7;
    const int t = threadIdx.x;
    const int w = t >> 6;
    const int lane = t & 63;
    const float* __restrict__ px = xyz + (size_t)b * Nn * 3;
    unsigned* bflag = flags + b * GFPS;
    unsigned long long* const kb0 = kbuf + b * GFPS;             // parity 0
    unsigned long long* const kb1 = kbuf + Bn * GFPS + b * GFPS; // parity 1

    float x[PPT], y[PPT], z[PPT], dist[PPT];
    const int base = g * (Nn / GFPS);
#pragma unroll
    for (int j = 0; j < PPT; ++j) {
        const int n = base + j * TFPS + t;
        x[j] = px[n * 3 + 0];
        y[j] = px[n * 3 + 1];
        z[j] = px[n * 3 + 2];
        dist[j] = __builtin_huge_valf();
    }
    float cx = px[0], cy = px[1], cz = px[2];
    if (g == 0 && t == 0) {
        fidx[b * Sn] = 0;
        newxyz[(size_t)b * Sn * 3 + 0] = cx;
        newxyz[(size_t)b * Sn * 3 + 1] = cy;
        newxyz[(size_t)b * Sn * 3 + 2] = cz;
    }

    for (int i = 0; i < Sn - 1; ++i) {
        // ---- update own 8 dists with centroid c_i, track thread max ----
        float bd = -1.0f;
#pragma unroll
        for (int j = 0; j < PPT; ++j) {
            const float dx = x[j] - cx;
            const float dy = y[j] - cy;
            const float dz = z[j] - cz;
            const float d = (dx * dx + dy * dy) + dz * dz;  // exact ref formula
            const float nd = fminf(dist[j], d);
            dist[j] = nd;
            bd = fmaxf(bd, nd);
        }
        // recover arg: smallest n matching bd (descending j, last write wins)
        unsigned bn = 0;
#pragma unroll
        for (int j = PPT - 1; j >= 0; --j)
            if (dist[j] == bd)
                bn = 0xFFFFFFFFu - (unsigned)(base + j * TFPS + t);
        unsigned long long key =
            ((unsigned long long)__float_as_uint(bd) << 32) |
            (unsigned long long)bn;
        // wave butterfly max (larger dist wins; tie -> smaller n via ~n)
#pragma unroll
        for (int off = 32; off > 0; off >>= 1) {
            const unsigned long long o = __shfl_xor(key, off);
            key = (o > key) ? o : key;
        }
        if (lane == 0) s_wk[w] = key;
        __syncthreads();
        // ---- wave 0: combine 4 wave keys, publish, poll peers, combine ----
        if (w == 0) {
            unsigned long long k2 = (lane < TFPS / 64) ? s_wk[lane] : 0ull;
#pragma unroll
            for (int off = 2; off > 0; off >>= 1) {
                const unsigned long long o = __shfl_xor(k2, off);
                k2 = (o > k2) ? o : k2;
            }
            unsigned long long* const kp = (i & 1) ? kb1 : kb0;
            if (lane == 0) {
                __hip_atomic_store(&kp[g], k2, __ATOMIC_RELAXED,
                                   __HIP_MEMORY_SCOPE_AGENT);
                __hip_atomic_store(&bflag[g], (unsigned)(i + 1),
                                   __ATOMIC_RELEASE, __HIP_MEMORY_SCOPE_AGENT);
            }
            unsigned long long kk = 0ull;
            if (lane < GFPS) {
                while (__hip_atomic_load(&bflag[lane], __ATOMIC_ACQUIRE,
                                         __HIP_MEMORY_SCOPE_AGENT)
                       < (unsigned)(i + 1)) { }
                kk = __hip_atomic_load(&kp[lane], __ATOMIC_RELAXED,
                                       __HIP_MEMORY_SCOPE_AGENT);
#pragma unroll
                for (int off = 4; off > 0; off >>= 1) {
                    const unsigned long long o = __shfl_xor(kk, off);
                    kk = (o > kk) ? o : kk;
                }
            }
            if (lane == 0) s_win = kk;
        }
        __syncthreads();
        const unsigned long long wk = s_win;
        const int wu = __builtin_amdgcn_readfirstlane(
            (int)(0xFFFFFFFFu - (unsigned)(wk & 0xFFFFFFFFull)));
        cx = px[3 * wu + 0];     // uniform scalar loads (L2)
        cy = px[3 * wu + 1];
        cz = px[3 * wu + 2];
        if (g == 0 && t == 0) {
            fidx[b * Sn + i + 1] = wu;
            newxyz[(size_t)(b * Sn + i + 1) * 3 + 0] = cx;
            newxyz[(size_t)(b * Sn + i + 1) * 3 + 1] = cy;
            newxyz[(size_t)(b * Sn + i + 1) * 3 + 2] = cz;
        }
    }
}

// ---------------------------------------------------------------------------
// Generic f32 GEMM: C[r,c] = sum_k Ain[r,k] * B^[k,c] + bias[c], N = 256 fixed.
// BT:  B^[k,c] = Bm[c*K + k] (conv_w.T), else Bm[k*256 + c] (fc1_w).
// AFF: A element transformed relu(a*asc[k] + ash[k])  (BN1+relu fused into load).
// 64x64 tile, 256 threads, 4x4 microtile, KC=16.
// ---------------------------------------------------------------------------
template <bool BT, bool AFF>
__global__ __launch_bounds__(256) void gemm_k(const float* __restrict__ A,
                                              const float* __restrict__ Bm,
                                              const float* __restrict__ bias,
                                              const float* __restrict__ asc,
                                              const float* __restrict__ ash,
                                              float* __restrict__ C, int K)
{
    __shared__ float As[16][64];
    __shared__ float Bs[16][64];
    const int t = threadIdx.x;
    const int tx = t & 15;
    const int ty = t >> 4;
    const int r0 = blockIdx.x * 64;
    const int c0 = blockIdx.y * 64;
    const int rrA = t >> 2;          // 0..63
    const int kkA = (t & 3) * 4;     // 0,4,8,12
    float acc[4][4] = {};
    for (int kc = 0; kc < K; kc += 16) {
        {   // stage A tile (transposed into [k][r])
            const float4 v = *reinterpret_cast<const float4*>(
                &A[(size_t)(r0 + rrA) * K + kc + kkA]);
            float vv[4] = {v.x, v.y, v.z, v.w};
#pragma unroll
            for (int m = 0; m < 4; ++m) {
                float xv = vv[m];
                if (AFF) {
                    const int k = kc + kkA + m;
                    xv = fmaxf(fmaf(xv, asc[k], ash[k]), 0.0f);
                }
                As[kkA + m][rrA] = xv;
            }
        }
        if (BT) {
            const float4 v = *reinterpret_cast<const float4*>(
                &Bm[(size_t)(c0 + rrA) * K + kc + kkA]);
            Bs[kkA + 0][rrA] = v.x;
            Bs[kkA + 1][rrA] = v.y;
            Bs[kkA + 2][rrA] = v.z;
            Bs[kkA + 3][rrA] = v.w;
        } else {
            const int kk = t >> 4;
            const int cc = (t & 15) * 4;
            const float4 v = *reinterpret_cast<const float4*>(
                &Bm[(size_t)(kc + kk) * DIMn + c0 + cc]);
            *reinterpret_cast<float4*>(&Bs[kk][cc]) = v;
        }
        __syncthreads();
#pragma unroll
        for (int kk = 0; kk < 16; ++kk) {
            const float4 a = *reinterpret_cast<const float4*>(&As[kk][ty * 4]);
            const float4 bv = *reinterpret_cast<const float4*>(&Bs[kk][tx * 4]);
            const float av[4] = {a.x, a.y, a.z, a.w};
            const float bw[4] = {bv.x, bv.y, bv.z, bv.w};
#pragma unroll
            for (int i = 0; i < 4; ++i)
#pragma unroll
                for (int j = 0; j < 4; ++j)
                    acc[i][j] = fmaf(av[i], bw[j], acc[i][j]);
        }
        __syncthreads();
    }
    const int c = c0 + tx * 4;
#pragma unroll
    for (int i = 0; i < 4; ++i) {
        float4 o;
        o.x = acc[i][0] + bias[c + 0];
        o.y = acc[i][1] + bias[c + 1];
        o.z = acc[i][2] + bias[c + 2];
        o.w = acc[i][3] + bias[c + 3];
        *reinterpret_cast<float4*>(&C[(size_t)(r0 + ty * 4 + i) * DIMn + c]) = o;
    }
}

// ---------------------------------------------------------------------------
// points_ori gather: pre[bs,:] = h0[fidx[bs],:]  (must run before h0 is
// overwritten by the residual update).
// ---------------------------------------------------------------------------
__global__ __launch_bounds__(256) void gather_po_kernel(const float* __restrict__ h0,
                                                        const int* __restrict__ fidx,
                                                        float* __restrict__ pre)
{
    const int bs = blockIdx.x;
    const int b = bs >> 11;
    const int fid = fidx[bs];
    pre[(size_t)bs * DIMn + threadIdx.x] =
        h0[((size_t)b * Nn + fid) * DIMn + threadIdx.x];
}

// ---------------------------------------------------------------------------
// per-channel partial sums (sum, sumsq) for BatchNorm stats; fixed order,
// no atomics -> deterministic.
// ---------------------------------------------------------------------------
__global__ __launch_bounds__(256) void stats_partial(const float* __restrict__ X,
                                                     int rowsPerBlk,
                                                     float* __restrict__ ps,
                                                     float* __restrict__ pq)
{
    const int c = threadIdx.x;
    const size_t r0 = (size_t)blockIdx.x * rowsPerBlk;
    float s = 0.0f, q = 0.0f;
    for (int r = 0; r < rowsPerBlk; ++r) {
        const float v = X[(r0 + r) * DIMn + c];
        s += v;
        q = fmaf(v, v, q);
    }
    ps[blockIdx.x * DIMn + c] = s;
    pq[blockIdx.x * DIMn + c] = q;
}

__global__ __launch_bounds__(256) void bn_finalize(const float* __restrict__ ps,
                                                   const float* __restrict__ pq,
                                                   int nblk, float invN,
                                                   const float* __restrict__ g,
                                                   const float* __restrict__ bb,
                                                   float* __restrict__ sc,
                                                   float* __restrict__ sh)
{
    const int c = threadIdx.x;
    float s = 0.0f, q = 0.0f;
    for (int i = 0; i < nblk; ++i) {
        s += ps[i * DIMn + c];
        q += pq[i * DIMn + c];
    }
    const float mean = s * invN;
    const float var = q * invN - mean * mean;   // biased var
    const float r = 1.0f / sqrtf(var + BNEPS);
    const float scale = g[c] * r;
    sc[c] = scale;
    sh[c] = bb[c] - mean * scale;
}

// ---------------------------------------------------------------------------
// h = h + relu(A2*sc + sh), in place on h0. float4 vectorized.
// ---------------------------------------------------------------------------
__global__ __launch_bounds__(256) void residual_kernel(float* __restrict__ h,
                                                       const float* __restrict__ a2,
                                                       const float* __restrict__ sc,
                                                       const float* __restrict__ sh)
{
    const size_t i = (size_t)blockIdx.x * 256 + threadIdx.x;
    const int c4 = (int)(i & 63);
    float4 hv = reinterpret_cast<float4*>(h)[i];
    const float4 av = reinterpret_cast<const float4*>(a2)[i];
    const float4 s4 = reinterpret_cast<const float4*>(sc)[c4];
    const float4 b4 = reinterpret_cast<const float4*>(sh)[c4];
    hv.x += fmaxf(fmaf(av.x, s4.x, b4.x), 0.0f);
    hv.y += fmaxf(fmaf(av.y, s4.y, b4.y), 0.0f);
    hv.z += fmaxf(fmaf(av.z, s4.z, b4.z), 0.0f);
    hv.w += fmaxf(fmaf(av.w, s4.w, b4.w), 0.0f);
    reinterpret_cast<float4*>(h)[i] = hv;
}

// ---------------------------------------------------------------------------
// K7: per-query exact 16-NN + gather + channel maxpool + residual add.
// One block per (b,s). Distances use the reference formula
// (qq + bb) - 2*ab with fp contract OFF, stored as sortable u32 keys in LDS
// (64 KB). 16 rounds of block-argmin with cached per-thread minimum; only the
// extraction owner rescans its 64 slots. Tie-break: (d, idx) lexicographic ==
// stable top_k. Then pre[bs,:] += max_k h[nidx_k,:].
// ---------------------------------------------------------------------------
__global__ __launch_bounds__(256) void topk_group(const float* __restrict__ xyz,
                                                  const float* __restrict__ newxyz,
                                                  const float* __restrict__ h,
                                                  float* __restrict__ pre)
{
#pragma clang fp contract(off)
    __shared__ unsigned s_key[Nn];              // 64 KB
    __shared__ unsigned long long s_wred[4];
    __shared__ unsigned long long s_win;
    __shared__ int s_nidx[KNEI];
    const int bs = blockIdx.x;
    const int b = bs >> 11;
    const int t = threadIdx.x;
    const float* px = xyz + (size_t)b * Nn * 3;
    const float qx = newxyz[bs * 3 + 0];
    const float qy = newxyz[bs * 3 + 1];
    const float qz = newxyz[bs * 3 + 2];
    const float qq = (qx * qx + qy * qy) + qz * qz;
    unsigned long long mkey = ~0ull;
#pragma unroll 4
    for (int u = 0; u < 64; ++u) {
        const int n = t + (u << 8);
        const float bx = px[n * 3 + 0];
        const float by = px[n * 3 + 1];
        const float bz = px[n * 3 + 2];
        const float bb2 = (bx * bx + by * by) + bz * bz;
        const float ab = (qx * bx + qy * by) + qz * bz;
        const float d = (qq + bb2) - 2.0f * ab;   // exact reference formula
        unsigned u32 = __float_as_uint(d);
        u32 = ((int)u32 < 0) ? ~u32 : (u32 | 0x80000000u);  // sortable transform
        s_key[n] = u32;
        const unsigned long long k = ((unsigned long long)u32 << 32) | (unsigned)n;
        mkey = (k < mkey) ? k : mkey;
    }
    __syncthreads();
    for (int r = 0; r < KNEI; ++r) {
        unsigned long long k = mkey;
#pragma unroll
        for (int off = 32; off > 0; off >>= 1) {
            const unsigned long long o = __shfl_xor(k, off);
            k = (o < k) ? o : k;
        }
        if ((t & 63) == 0) s_wred[t >> 6] = k;
        __syncthreads();
        if (t == 0) {
            unsigned long long w = s_wred[0];
            if (s_wred[1] < w) w = s_wred[1];
            if (s_wred[2] < w) w = s_wred[2];
            if (s_wred[3] < w) w = s_wred[3];
            s_win = w;
            s_nidx[r] = (int)(unsigned)(w & 0xFFFFFFFFull);
        }
        __syncthreads();
        const unsigned long long w = s_win;
        if (w == mkey) {  // unique owner: invalidate + rescan own 64 slots
            const int wn = (int)(unsigned)(w & 0xFFFFFFFFull);
            s_key[wn] = 0xFFFFFFFFu;
            mkey = ~0ull;
#pragma unroll 4
            for (int u = 0; u < 64; ++u) {
                const int n = t + (u << 8);
                const unsigned long long kk =
                    ((unsigned long long)s_key[n] << 32) | (unsigned)n;
                mkey = (kk < mkey) ? kk : mkey;
            }
        }
        __syncthreads();
    }
    // gather + maxpool + add points_ori (already in pre)
    const float po = pre[(size_t)bs * DIMn + t];
    float m = -__builtin_huge_valf();
#pragma unroll
    for (int r = 0; r < KNEI; ++r) {
        const int n = s_nidx[r];
        m = fmaxf(m, h[((size_t)b * Nn + n) * DIMn + t]);
    }
    pre[(size_t)bs * DIMn + t] = po + m;
}

// ---------------------------------------------------------------------------
// final BN apply: out = pre*sc + sh
// ---------------------------------------------------------------------------
__global__ __launch_bounds__(256) void apply_bn_kernel(const float* __restrict__ pre,
                                                       const float* __restrict__ sc,
                                                       const float* __restrict__ sh,
                                                       float* __restrict__ out)
{
    const size_t i = (size_t)blockIdx.x * 256 + threadIdx.x;
    const int c4 = (int)(i & 63);
    const float4 v = reinterpret_cast<const float4*>(pre)[i];
    const float4 s4 = reinterpret_cast<const float4*>(sc)[c4];
    const float4 b4 = reinterpret_cast<const float4*>(sh)[c4];
    float4 o;
    o.x = fmaf(v.x, s4.x, b4.x);
    o.y = fmaf(v.y, s4.y, b4.y);
    o.z = fmaf(v.z, s4.z, b4.z);
    o.w = fmaf(v.w, s4.w, b4.w);
    reinterpret_cast<float4*>(out)[i] = o;
}

// ---------------------------------------------------------------------------
// Launch. Workspace layout (bytes), requires ws_size >= ~211 MB:
//   [0,64Mi)      h0  (fc1 out, then final h after residual)
//   [64Mi,128Mi)  A1  (conv1 pre-BN)
//   [128Mi,192Mi) A2  (conv2 pre-BN)
//   [192Mi,200Mi) pre (points_ori, then new_points pre-BN)  8 MB
//   [200Mi,+32K)  fps_idx
//   [201Mi, ...)  ps/pq partials (512 KB) + 6x256 scale/shift
//   [202Mi, ...)  fps comm: flags[32] u32 + kbuf[2][32] u64
// ---------------------------------------------------------------------------
extern "C" void kernel_launch(void* const* d_in, const int* in_sizes, int n_in,
                              void* d_out, int out_size, void* d_ws, size_t ws_size,
                              hipStream_t stream)
{
    (void)in_sizes; (void)n_in; (void)out_size; (void)ws_size;
    const float* xyz     = (const float*)d_in[0];
    const float* points  = (const float*)d_in[1];
    const float* fc1_w   = (const float*)d_in[2];
    const float* fc1_b   = (const float*)d_in[3];
    const float* conv1_w = (const float*)d_in[4];
    const float* conv1_b = (const float*)d_in[5];
    const float* conv2_w = (const float*)d_in[6];
    const float* conv2_b = (const float*)d_in[7];
    const float* bn1_g   = (const float*)d_in[8];
    const float* bn1_b   = (const float*)d_in[9];
    const float* bn2_g   = (const float*)d_in[10];
    const float* bn2_b   = (const float*)d_in[11];
    const float* bn_g    = (const float*)d_in[12];
    const float* bn_b    = (const float*)d_in[13];

    float* out = (float*)d_out;
    float* newxyz = out;                       // [4,2048,3]
    float* outpts = out + (size_t)Bn * Sn * 3; // [4,2048,256]

    char* w = (char*)d_ws;
    float* h0   = (float*)(w);
    float* A1   = (float*)(w + (64ull << 20));
    float* A2   = (float*)(w + (128ull << 20));
    float* pre  = (float*)(w + (192ull << 20));
    int*   fidx = (int*)  (w + (200ull << 20));
    float* ps   = (float*)(w + (201ull << 20));
    float* pq   = ps + 256 * 256;
    float* sc1  = pq + 256 * 256;
    float* sh1  = sc1 + 256;
    float* sc2  = sh1 + 256;
    float* sh2  = sc2 + 256;
    float* sc3  = sh2 + 256;
    float* sh3  = sc3 + 256;
    unsigned* fflags = (unsigned*)(w + (202ull << 20));
    unsigned long long* fkbuf = (unsigned long long*)(w + (202ull << 20) + 256);

    // 1. FPS: zero flags, then 32 cooperating WGs (8 per batch)
    fps_zero_kernel<<<1, 64, 0, stream>>>(fflags);
    fps_kernel<<<Bn * GFPS, TFPS, 0, stream>>>(xyz, fidx, newxyz, fflags, fkbuf);
    // 2. h0 = points @ fc1_w + fc1_b
    gemm_k<false, false><<<dim3(MROWS / 64, DIMn / 64), 256, 0, stream>>>(
        points, fc1_w, fc1_b, nullptr, nullptr, h0, CINn);
    // 3. points_ori = h0[fps_idx]  (gathered BEFORE h0 is updated)
    gather_po_kernel<<<SROWS, 256, 0, stream>>>(h0, fidx, pre);
    // 4. A1 = h0 @ conv1_w.T + conv1_b ; BN1 stats
    gemm_k<true, false><<<dim3(MROWS / 64, DIMn / 64), 256, 0, stream>>>(
        h0, conv1_w, conv1_b, nullptr, nullptr, A1, DIMn);
    stats_partial<<<256, 256, 0, stream>>>(A1, MROWS / 256, ps, pq);
    bn_finalize<<<1, 256, 0, stream>>>(ps, pq, 256, 1.0f / MROWS, bn1_g, bn1_b, sc1, sh1);
    // 5. A2 = relu(BN1(A1)) @ conv2_w.T + conv2_b ; BN2 stats
    gemm_k<true, true><<<dim3(MROWS / 64, DIMn / 64), 256, 0, stream>>>(
        A1, conv2_w, conv2_b, sc1, sh1, A2, DIMn);
    stats_partial<<<256, 256, 0, stream>>>(A2, MROWS / 256, ps, pq);
    bn_finalize<<<1, 256, 0, stream>>>(ps, pq, 256, 1.0f / MROWS, bn2_g, bn2_b, sc2, sh2);
    // 6. h0 += relu(BN2(A2))   (h0 becomes final h)
    residual_kernel<<<(MROWS * DIMn / 4) / 256, 256, 0, stream>>>(h0, A2, sc2, sh2);
    // 7. 16-NN + gather + maxpool: pre = points_ori + max_k h[idx_k]
    topk_group<<<SROWS, 256, 0, stream>>>(xyz, newxyz, h0, pre);
    // 8. final BN over [B*S, D]
    stats_partial<<<64, 256, 0, stream>>>(pre, SROWS / 64, ps, pq);
    bn_finalize<<<1, 256, 0, stream>>>(ps, pq, 64, 1.0f / SROWS, bn_g, bn_b, sc3, sh3);
    apply_bn_kernel<<<(SROWS * DIMn / 4) / 256, 256, 0, stream>>>(pre, sc3, sh3, outpts);
}

// Round 7
// 4667.984 us; speedup vs baseline: 1.5332x; 1.5332x over previous
//
#include <hip/hip_runtime.h>
#include <math.h>

// Problem constants (fixed by setup_inputs)
#define Bn   4
#define Nn   16384
#define CINn 32
#define DIMn 256
#define Sn   2048
#define KNEI 16
#define BNEPS 1e-5f
#define MROWS (Bn * Nn)   // 65536
#define SROWS (Bn * Sn)   // 8192

// ---------------------------------------------------------------------------
// DPP max helpers (VALU pipe, no LDS traffic). For wave64 max-reduce into
// lane 63: row_shr 1/2/4/8 then row_bcast15 (rows 1,3) + row_bcast31
// (rows 2,3). old=0 / bound_ctrl=true zero-fill is a valid identity because
// all reduced values are >= 0 (nonneg f32 bits / u32 keys).
// ---------------------------------------------------------------------------
#define UMAX_DPP(v, ctl, rmask)                                               \
    {                                                                         \
        unsigned _o = (unsigned)__builtin_amdgcn_update_dpp(                  \
            0, (int)(v), (ctl), (rmask), 0xf, true);                          \
        (v) = ((v) > _o) ? (v) : _o;                                          \
    }
#define WAVE_UMAX64(v)                                                        \
    UMAX_DPP(v, 0x111, 0xf) UMAX_DPP(v, 0x112, 0xf) UMAX_DPP(v, 0x114, 0xf)  \
    UMAX_DPP(v, 0x118, 0xf) UMAX_DPP(v, 0x142, 0xa) UMAX_DPP(v, 0x143, 0xc)
// u64 (hi,lo) max across lanes 0..15 (row 0), result in lane 15
#define U64MAX_DPP16(khi, klo, ctl)                                           \
    {                                                                         \
        unsigned _lo2 = (unsigned)__builtin_amdgcn_update_dpp(                \
            0, (int)(klo), (ctl), 0xf, 0xf, true);                            \
        unsigned _hi2 = (unsigned)__builtin_amdgcn_update_dpp(                \
            0, (int)(khi), (ctl), 0xf, 0xf, true);                            \
        const bool _g = (_hi2 > (khi)) || (_hi2 == (khi) && _lo2 > (klo));    \
        (khi) = _g ? _hi2 : (khi);                                            \
        (klo) = _g ? _lo2 : (klo);                                            \
    }

// ---------------------------------------------------------------------------
// K1: furthest point sampling, v7.
// Lessons consolidated (r2-r6 counters):
//  * launch_bounds 2nd arg acts as min-BLOCKS/CU on this toolchain: (512,2)
//    -> 128 VGPR budget (r2 remat), (1024,4) -> 2-block target -> 64 budget
//    (r4 fit 32 floats, r5's 79 spilled to scratch). So: force ONE block/CU
//    via >80KB LDS -> guaranteed 128-VGPR budget for 16 waves.
//  * Cross-WG per-iteration sync costs ~2.9us (r6) -> single WG per batch.
//  * r4's DS-pipe tail (u64 __shfl_xor butterflies on 16 waves ~2000cy/iter)
//    was as expensive as the update -> replace ALL cross-lane reduces with
//    DPP (VALU pipe).
// Data plane: x in LDS (padded stride 20 floats/thread -> ds_read_b128
// conflict-free: lane t covers banks (20t)%32..+3, 8-lane period covers all
// 32 banks exactly once); y,z,dist in VGPRs (48 floats, pinned).
// Numerics identical to reference: contract OFF, d=(dx*dx+dy*dy)+dz*dz,
// running fminf, argmax tie -> lowest ORIGINAL index via key=(dist, ~n),
// ties within thread resolved to smallest n by descending-j scan.
// Thread t owns points n = 16t+j (contiguous), j=0..15.
// ---------------------------------------------------------------------------
__global__ __launch_bounds__(1024, 1) void fps_kernel(const float* __restrict__ xyz,
                                                      int* __restrict__ fidx,
                                                      float* __restrict__ newxyz)
{
#pragma clang fp contract(off)
    __shared__ float sx[1024 * 20];               // 80 KB -> 1 block/CU
    __shared__ unsigned long long s_wk[2][16];
    const int b = blockIdx.x;
    const int t = threadIdx.x;
    const int w = t >> 6;
    const int lane = t & 63;
    const float* __restrict__ px = xyz + (size_t)b * Nn * 3;

    float y[16], z[16], dist[16];
    // init: thread t reads its 48 consecutive floats (points 16t..16t+15)
#pragma unroll
    for (int a = 0; a < 12; ++a) {
        const float4 v = *reinterpret_cast<const float4*>(&px[48 * t + 4 * a]);
        const float e[4] = {v.x, v.y, v.z, v.w};
#pragma unroll
        for (int c = 0; c < 4; ++c) {
            const int flat = 4 * a + c;           // 0..47 = 3*j + comp
            const int j = flat / 3;
            const int comp = flat - 3 * j;
            if (comp == 0) sx[20 * t + j] = e[c];
            else if (comp == 1) y[j] = e[c];
            else z[j] = e[c];
        }
    }
#pragma unroll
    for (int j = 0; j < 16; ++j) {
        dist[j] = __builtin_huge_valf();
        asm volatile("" : "+v"(y[j]));
        asm volatile("" : "+v"(z[j]));
    }
    float cx = px[0], cy = px[1], cz = px[2];
    if (t == 0) {
        fidx[b * Sn] = 0;
        newxyz[(size_t)b * Sn * 3 + 0] = cx;
        newxyz[(size_t)b * Sn * 3 + 1] = cy;
        newxyz[(size_t)b * Sn * 3 + 2] = cz;
    }
    __syncthreads();

    for (int i = 0; i < Sn - 1; ++i) {
        // ---- update 16 dists, track thread max --------------------------
        float bd = -1.0f;
#pragma unroll
        for (int a = 0; a < 4; ++a) {
            const float4 q = *reinterpret_cast<const float4*>(&sx[20 * t + 4 * a]);
            const float xv[4] = {q.x, q.y, q.z, q.w};
#pragma unroll
            for (int c = 0; c < 4; ++c) {
                const int j = 4 * a + c;
                const float dx = xv[c] - cx;
                const float dy = y[j] - cy;
                const float dz = z[j] - cz;
                const float d = (dx * dx + dy * dy) + dz * dz;  // no fma
                const float nd = fminf(dist[j], d);
                dist[j] = nd;
                bd = fmaxf(bd, nd);
            }
        }
        // recover arg: smallest n matching bd (descending j, last write wins)
        unsigned bn = 0;
#pragma unroll
        for (int j = 15; j >= 0; --j)
            if (dist[j] == bd) bn = 0xFFFFFFFFu - (unsigned)(16 * t + j);
        // ---- wave reduce via DPP (nonneg f32 bits ~ u32 order) ----------
        unsigned bdu = __float_as_uint(bd);
        unsigned m = bdu;
        WAVE_UMAX64(m)
        const unsigned bdw = (unsigned)__builtin_amdgcn_readlane((int)m, 63);
        unsigned q2 = (bdu == bdw) ? bn : 0u;
        WAVE_UMAX64(q2)
        const unsigned bnw = (unsigned)__builtin_amdgcn_readlane((int)q2, 63);
        if (lane == 0)
            s_wk[i & 1][w] = ((unsigned long long)bdw << 32) | bnw;
        __syncthreads();
        // ---- cross-wave: 16 entries, u64 DPP max in lanes 0..15 ---------
        const unsigned long long kk =
            (lane < 16) ? s_wk[i & 1][lane] : 0ull;
        unsigned klo = (unsigned)kk;
        unsigned khi = (unsigned)(kk >> 32);
        U64MAX_DPP16(khi, klo, 0x111)
        U64MAX_DPP16(khi, klo, 0x112)
        U64MAX_DPP16(khi, klo, 0x114)
        U64MAX_DPP16(khi, klo, 0x118)
        const unsigned bnf = (unsigned)__builtin_amdgcn_readlane((int)klo, 15);
        const int wu = (int)(0xFFFFFFFFu - bnf);
        cx = px[3 * wu + 0];                      // uniform scalar loads (L2)
        cy = px[3 * wu + 1];
        cz = px[3 * wu + 2];
        if (t == 0) {
            fidx[b * Sn + i + 1] = wu;
            newxyz[(size_t)(b * Sn + i + 1) * 3 + 0] = cx;
            newxyz[(size_t)(b * Sn + i + 1) * 3 + 1] = cy;
            newxyz[(size_t)(b * Sn + i + 1) * 3 + 2] = cz;
        }
    }
}

// ---------------------------------------------------------------------------
// Generic f32 GEMM: C[r,c] = sum_k Ain[r,k] * B^[k,c] + bias[c], N = 256 fixed.
// BT:  B^[k,c] = Bm[c*K + k] (conv_w.T), else Bm[k*256 + c] (fc1_w).
// AFF: A element transformed relu(a*asc[k] + ash[k])  (BN1+relu fused into load).
// 64x64 tile, 256 threads, 4x4 microtile, KC=16.
// ---------------------------------------------------------------------------
template <bool BT, bool AFF>
__global__ __launch_bounds__(256) void gemm_k(const float* __restrict__ A,
                                              const float* __restrict__ Bm,
                                              const float* __restrict__ bias,
                                              const float* __restrict__ asc,
                                              const float* __restrict__ ash,
                                              float* __restrict__ C, int K)
{
    __shared__ float As[16][64];
    __shared__ float Bs[16][64];
    const int t = threadIdx.x;
    const int tx = t & 15;
    const int ty = t >> 4;
    const int r0 = blockIdx.x * 64;
    const int c0 = blockIdx.y * 64;
    const int rrA = t >> 2;          // 0..63
    const int kkA = (t & 3) * 4;     // 0,4,8,12
    float acc[4][4] = {};
    for (int kc = 0; kc < K; kc += 16) {
        {   // stage A tile (transposed into [k][r])
            const float4 v = *reinterpret_cast<const float4*>(
                &A[(size_t)(r0 + rrA) * K + kc + kkA]);
            float vv[4] = {v.x, v.y, v.z, v.w};
#pragma unroll
            for (int m = 0; m < 4; ++m) {
                float xv = vv[m];
                if (AFF) {
                    const int k = kc + kkA + m;
                    xv = fmaxf(fmaf(xv, asc[k], ash[k]), 0.0f);
                }
                As[kkA + m][rrA] = xv;
            }
        }
        if (BT) {
            const float4 v = *reinterpret_cast<const float4*>(
                &Bm[(size_t)(c0 + rrA) * K + kc + kkA]);
            Bs[kkA + 0][rrA] = v.x;
            Bs[kkA + 1][rrA] = v.y;
            Bs[kkA + 2][rrA] = v.z;
            Bs[kkA + 3][rrA] = v.w;
        } else {
            const int kk = t >> 4;
            const int cc = (t & 15) * 4;
            const float4 v = *reinterpret_cast<const float4*>(
                &Bm[(size_t)(kc + kk) * DIMn + c0 + cc]);
            *reinterpret_cast<float4*>(&Bs[kk][cc]) = v;
        }
        __syncthreads();
#pragma unroll
        for (int kk = 0; kk < 16; ++kk) {
            const float4 a = *reinterpret_cast<const float4*>(&As[kk][ty * 4]);
            const float4 bv = *reinterpret_cast<const float4*>(&Bs[kk][tx * 4]);
            const float av[4] = {a.x, a.y, a.z, a.w};
            const float bw[4] = {bv.x, bv.y, bv.z, bv.w};
#pragma unroll
            for (int i = 0; i < 4; ++i)
#pragma unroll
                for (int j = 0; j < 4; ++j)
                    acc[i][j] = fmaf(av[i], bw[j], acc[i][j]);
        }
        __syncthreads();
    }
    const int c = c0 + tx * 4;
#pragma unroll
    for (int i = 0; i < 4; ++i) {
        float4 o;
        o.x = acc[i][0] + bias[c + 0];
        o.y = acc[i][1] + bias[c + 1];
        o.z = acc[i][2] + bias[c + 2];
        o.w = acc[i][3] + bias[c + 3];
        *reinterpret_cast<float4*>(&C[(size_t)(r0 + ty * 4 + i) * DIMn + c]) = o;
    }
}

// ---------------------------------------------------------------------------
// points_ori gather: pre[bs,:] = h0[fidx[bs],:]  (must run before h0 is
// overwritten by the residual update).
// ---------------------------------------------------------------------------
__global__ __launch_bounds__(256) void gather_po_kernel(const float* __restrict__ h0,
                                                        const int* __restrict__ fidx,
                                                        float* __restrict__ pre)
{
    const int bs = blockIdx.x;
    const int b = bs >> 11;
    const int fid = fidx[bs];
    pre[(size_t)bs * DIMn + threadIdx.x] =
        h0[((size_t)b * Nn + fid) * DIMn + threadIdx.x];
}

// ---------------------------------------------------------------------------
// per-channel partial sums (sum, sumsq) for BatchNorm stats; fixed order,
// no atomics -> deterministic.
// ---------------------------------------------------------------------------
__global__ __launch_bounds__(256) void stats_partial(const float* __restrict__ X,
                                                     int rowsPerBlk,
                                                     float* __restrict__ ps,
                                                     float* __restrict__ pq)
{
    const int c = threadIdx.x;
    const size_t r0 = (size_t)blockIdx.x * rowsPerBlk;
    float s = 0.0f, q = 0.0f;
    for (int r = 0; r < rowsPerBlk; ++r) {
        const float v = X[(r0 + r) * DIMn + c];
        s += v;
        q = fmaf(v, v, q);
    }
    ps[blockIdx.x * DIMn + c] = s;
    pq[blockIdx.x * DIMn + c] = q;
}

__global__ __launch_bounds__(256) void bn_finalize(const float* __restrict__ ps,
                                                   const float* __restrict__ pq,
                                                   int nblk, float invN,
                                                   const float* __restrict__ g,
                                                   const float* __restrict__ bb,
                                                   float* __restrict__ sc,
                                                   float* __restrict__ sh)
{
    const int c = threadIdx.x;
    float s = 0.0f, q = 0.0f;
    for (int i = 0; i < nblk; ++i) {
        s += ps[i * DIMn + c];
        q += pq[i * DIMn + c];
    }
    const float mean = s * invN;
    const float var = q * invN - mean * mean;   // biased var
    const float r = 1.0f / sqrtf(var + BNEPS);
    const float scale = g[c] * r;
    sc[c] = scale;
    sh[c] = bb[c] - mean * scale;
}

// ---------------------------------------------------------------------------
// h = h + relu(A2*sc + sh), in place on h0. float4 vectorized.
// ---------------------------------------------------------------------------
__global__ __launch_bounds__(256) void residual_kernel(float* __restrict__ h,
                                                       const float* __restrict__ a2,
                                                       const float* __restrict__ sc,
                                                       const float* __restrict__ sh)
{
    const size_t i = (size_t)blockIdx.x * 256 + threadIdx.x;
    const int c4 = (int)(i & 63);
    float4 hv = reinterpret_cast<float4*>(h)[i];
    const float4 av = reinterpret_cast<const float4*>(a2)[i];
    const float4 s4 = reinterpret_cast<const float4*>(sc)[c4];
    const float4 b4 = reinterpret_cast<const float4*>(sh)[c4];
    hv.x += fmaxf(fmaf(av.x, s4.x, b4.x), 0.0f);
    hv.y += fmaxf(fmaf(av.y, s4.y, b4.y), 0.0f);
    hv.z += fmaxf(fmaf(av.z, s4.z, b4.z), 0.0f);
    hv.w += fmaxf(fmaf(av.w, s4.w, b4.w), 0.0f);
    reinterpret_cast<float4*>(h)[i] = hv;
}

// ---------------------------------------------------------------------------
// K7: per-query exact 16-NN + gather + channel maxpool + residual add.
// One block per (b,s). Distances use the reference formula
// (qq + bb) - 2*ab with fp contract OFF, stored as sortable u32 keys in LDS
// (64 KB). 16 rounds of block-argmin with cached per-thread minimum; only the
// extraction owner rescans its 64 slots. Tie-break: (d, idx) lexicographic ==
// stable top_k. Then pre[bs,:] += max_k h[nidx_k,:].
// ---------------------------------------------------------------------------
__global__ __launch_bounds__(256) void topk_group(const float* __restrict__ xyz,
                                                  const float* __restrict__ newxyz,
                                                  const float* __restrict__ h,
                                                  float* __restrict__ pre)
{
#pragma clang fp contract(off)
    __shared__ unsigned s_key[Nn];              // 64 KB
    __shared__ unsigned long long s_wred[4];
    __shared__ unsigned long long s_win;
    __shared__ int s_nidx[KNEI];
    const int bs = blockIdx.x;
    const int b = bs >> 11;
    const int t = threadIdx.x;
    const float* px = xyz + (size_t)b * Nn * 3;
    const float qx = newxyz[bs * 3 + 0];
    const float qy = newxyz[bs * 3 + 1];
    const float qz = newxyz[bs * 3 + 2];
    const float qq = (qx * qx + qy * qy) + qz * qz;
    unsigned long long mkey = ~0ull;
#pragma unroll 4
    for (int u = 0; u < 64; ++u) {
        const int n = t + (u << 8);
        const float bx = px[n * 3 + 0];
        const float by = px[n * 3 + 1];
        const float bz = px[n * 3 + 2];
        const float bb2 = (bx * bx + by * by) + bz * bz;
        const float ab = (qx * bx + qy * by) + qz * bz;
        const float d = (qq + bb2) - 2.0f * ab;   // exact reference formula
        unsigned u32 = __float_as_uint(d);
        u32 = ((int)u32 < 0) ? ~u32 : (u32 | 0x80000000u);  // sortable transform
        s_key[n] = u32;
        const unsigned long long k = ((unsigned long long)u32 << 32) | (unsigned)n;
        mkey = (k < mkey) ? k : mkey;
    }
    __syncthreads();
    for (int r = 0; r < KNEI; ++r) {
        unsigned long long k = mkey;
#pragma unroll
        for (int off = 32; off > 0; off >>= 1) {
            const unsigned long long o = __shfl_xor(k, off);
            k = (o < k) ? o : k;
        }
        if ((t & 63) == 0) s_wred[t >> 6] = k;
        __syncthreads();
        if (t == 0) {
            unsigned long long w = s_wred[0];
            if (s_wred[1] < w) w = s_wred[1];
            if (s_wred[2] < w) w = s_wred[2];
            if (s_wred[3] < w) w = s_wred[3];
            s_win = w;
            s_nidx[r] = (int)(unsigned)(w & 0xFFFFFFFFull);
        }
        __syncthreads();
        const unsigned long long w = s_win;
        if (w == mkey) {  // unique owner: invalidate + rescan own 64 slots
            const int wn = (int)(unsigned)(w & 0xFFFFFFFFull);
            s_key[wn] = 0xFFFFFFFFu;
            mkey = ~0ull;
#pragma unroll 4
            for (int u = 0; u < 64; ++u) {
                const int n = t + (u << 8);
                const unsigned long long kk =
                    ((unsigned long long)s_key[n] << 32) | (unsigned)n;
                mkey = (kk < mkey) ? kk : mkey;
            }
        }
        __syncthreads();
    }
    // gather + maxpool + add points_ori (already in pre)
    const float po = pre[(size_t)bs * DIMn + t];
    float m = -__builtin_huge_valf();
#pragma unroll
    for (int r = 0; r < KNEI; ++r) {
        const int n = s_nidx[r];
        m = fmaxf(m, h[((size_t)b * Nn + n) * DIMn + t]);
    }
    pre[(size_t)bs * DIMn + t] = po + m;
}

// ---------------------------------------------------------------------------
// final BN apply: out = pre*sc + sh
// ---------------------------------------------------------------------------
__global__ __launch_bounds__(256) void apply_bn_kernel(const float* __restrict__ pre,
                                                       const float* __restrict__ sc,
                                                       const float* __restrict__ sh,
                                                       float* __restrict__ out)
{
    const size_t i = (size_t)blockIdx.x * 256 + threadIdx.x;
    const int c4 = (int)(i & 63);
    const float4 v = reinterpret_cast<const float4*>(pre)[i];
    const float4 s4 = reinterpret_cast<const float4*>(sc)[c4];
    const float4 b4 = reinterpret_cast<const float4*>(sh)[c4];
    float4 o;
    o.x = fmaf(v.x, s4.x, b4.x);
    o.y = fmaf(v.y, s4.y, b4.y);
    o.z = fmaf(v.z, s4.z, b4.z);
    o.w = fmaf(v.w, s4.w, b4.w);
    reinterpret_cast<float4*>(out)[i] = o;
}

// ---------------------------------------------------------------------------
// Launch. Workspace layout (bytes), requires ws_size >= ~211 MB:
//   [0,64Mi)      h0  (fc1 out, then final h after residual)
//   [64Mi,128Mi)  A1  (conv1 pre-BN)
//   [128Mi,192Mi) A2  (conv2 pre-BN)
//   [192Mi,200Mi) pre (points_ori, then new_points pre-BN)  8 MB
//   [200Mi,+32K)  fps_idx
//   [201Mi, ...)  ps/pq partials (512 KB) + 6x256 scale/shift
// ---------------------------------------------------------------------------
extern "C" void kernel_launch(void* const* d_in, const int* in_sizes, int n_in,
                              void* d_out, int out_size, void* d_ws, size_t ws_size,
                              hipStream_t stream)
{
    (void)in_sizes; (void)n_in; (void)out_size; (void)ws_size;
    const float* xyz     = (const float*)d_in[0];
    const float* points  = (const float*)d_in[1];
    const float* fc1_w   = (const float*)d_in[2];
    const float* fc1_b   = (const float*)d_in[3];
    const float* conv1_w = (const float*)d_in[4];
    const float* conv1_b = (const float*)d_in[5];
    const float* conv2_w = (const float*)d_in[6];
    const float* conv2_b = (const float*)d_in[7];
    const float* bn1_g   = (const float*)d_in[8];
    const float* bn1_b   = (const float*)d_in[9];
    const float* bn2_g   = (const float*)d_in[10];
    const float* bn2_b   = (const float*)d_in[11];
    const float* bn_g    = (const float*)d_in[12];
    const float* bn_b    = (const float*)d_in[13];

    float* out = (float*)d_out;
    float* newxyz = out;                       // [4,2048,3]
    float* outpts = out + (size_t)Bn * Sn * 3; // [4,2048,256]

    char* w = (char*)d_ws;
    float* h0   = (float*)(w);
    float* A1   = (float*)(w + (64ull << 20));
    float* A2   = (float*)(w + (128ull << 20));
    float* pre  = (float*)(w + (192ull << 20));
    int*   fidx = (int*)  (w + (200ull << 20));
    float* ps   = (float*)(w + (201ull << 20));
    float* pq   = ps + 256 * 256;
    float* sc1  = pq + 256 * 256;
    float* sh1  = sc1 + 256;
    float* sc2  = sh1 + 256;
    float* sh2  = sc2 + 256;
    float* sc3  = sh2 + 256;
    float* sh3  = sc3 + 256;

    // 1. FPS (writes fps_idx + new_xyz directly into d_out)
    fps_kernel<<<Bn, 1024, 0, stream>>>(xyz, fidx, newxyz);
    // 2. h0 = points @ fc1_w + fc1_b
    gemm_k<false, false><<<dim3(MROWS / 64, DIMn / 64), 256, 0, stream>>>(
        points, fc1_w, fc1_b, nullptr, nullptr, h0, CINn);
    // 3. points_ori = h0[fps_idx]  (gathered BEFORE h0 is updated)
    gather_po_kernel<<<SROWS, 256, 0, stream>>>(h0, fidx, pre);
    // 4. A1 = h0 @ conv1_w.T + conv1_b ; BN1 stats
    gemm_k<true, false><<<dim3(MROWS / 64, DIMn / 64), 256, 0, stream>>>(
        h0, conv1_w, conv1_b, nullptr, nullptr, A1, DIMn);
    stats_partial<<<256, 256, 0, stream>>>(A1, MROWS / 256, ps, pq);
    bn_finalize<<<1, 256, 0, stream>>>(ps, pq, 256, 1.0f / MROWS, bn1_g, bn1_b, sc1, sh1);
    // 5. A2 = relu(BN1(A1)) @ conv2_w.T + conv2_b ; BN2 stats
    gemm_k<true, true><<<dim3(MROWS / 64, DIMn / 64), 256, 0, stream>>>(
        A1, conv2_w, conv2_b, sc1, sh1, A2, DIMn);
    stats_partial<<<256, 256, 0, stream>>>(A2, MROWS / 256, ps, pq);
    bn_finalize<<<1, 256, 0, stream>>>(ps, pq, 256, 1.0f / MROWS, bn2_g, bn2_b, sc2, sh2);
    // 6. h0 += relu(BN2(A2))   (h0 becomes final h)
    residual_kernel<<<(MROWS * DIMn / 4) / 256, 256, 0, stream>>>(h0, A2, sc2, sh2);
    // 7. 16-NN + gather + maxpool: pre = points_ori + max_k h[idx_k]
    topk_group<<<SROWS, 256, 0, stream>>>(xyz, newxyz, h0, pre);
    // 8. final BN over [B*S, D]
    stats_partial<<<64, 256, 0, stream>>>(pre, SROWS / 64, ps, pq);
    bn_finalize<<<1, 256, 0, stream>>>(ps, pq, 64, 1.0f / SROWS, bn_g, bn_b, sc3, sh3);
    apply_bn_kernel<<<(SROWS * DIMn / 4) / 256, 256, 0, stream>>>(pre, sc3, sh3, outpts);
}

// Round 8
// 4095.835 us; speedup vs baseline: 1.7474x; 1.1397x over previous
//
#include <hip/hip_runtime.h>
#include <math.h>

// Problem constants (fixed by setup_inputs)
#define Bn   4
#define Nn   16384
#define CINn 32
#define DIMn 256
#define Sn   2048
#define KNEI 16
#define BNEPS 1e-5f
#define MROWS (Bn * Nn)   // 65536
#define SROWS (Bn * Sn)   // 8192

#define NWORK 248                 // worker blocks
#define NBLK  (NWORK + Bn)        // 252 total blocks (<=256 CUs, 1/CU via LDS)

struct FusedSync {
    unsigned stage[8];            // stage completion counters (workers)
    unsigned prog[Bn];            // FPS progress per batch (multiples of 256)
};

// ---------------------------------------------------------------------------
// DPP max helpers (VALU pipe). Identity 0 valid: reduced values >= 0.
// ---------------------------------------------------------------------------
#define UMAX_DPP(v, ctl, rmask)                                               \
    {                                                                         \
        unsigned _o = (unsigned)__builtin_amdgcn_update_dpp(                  \
            0, (int)(v), (ctl), (rmask), 0xf, true);                          \
        (v) = ((v) > _o) ? (v) : _o;                                          \
    }
#define WAVE_UMAX64(v)                                                        \
    UMAX_DPP(v, 0x111, 0xf) UMAX_DPP(v, 0x112, 0xf) UMAX_DPP(v, 0x114, 0xf)  \
    UMAX_DPP(v, 0x118, 0xf) UMAX_DPP(v, 0x142, 0xa) UMAX_DPP(v, 0x143, 0xc)
#define U64MAX_DPP16(khi, klo, ctl)                                           \
    {                                                                         \
        unsigned _lo2 = (unsigned)__builtin_amdgcn_update_dpp(                \
            0, (int)(klo), (ctl), 0xf, 0xf, true);                            \
        unsigned _hi2 = (unsigned)__builtin_amdgcn_update_dpp(                \
            0, (int)(khi), (ctl), 0xf, 0xf, true);                            \
        const bool _g = (_hi2 > (khi)) || (_hi2 == (khi) && _lo2 > (klo));    \
        (khi) = _g ? _hi2 : (khi);                                            \
        (klo) = _g ? _lo2 : (klo);                                            \
    }

__global__ __launch_bounds__(64) void fps_zero_kernel(unsigned* __restrict__ s)
{
    if (threadIdx.x < 12) s[threadIdx.x] = 0u;
}

// ---------------------------------------------------------------------------
// 64x64 GEMM tile computed by one 256-thread team (4 teams per 1024-block).
// Barrier counts uniform across teams (act guards data ops only).
// ---------------------------------------------------------------------------
template <bool BT, bool AFF>
__device__ void gemm_team(const float* A, const float* Bm, const float* bias,
                          const float* asc, const float* ash, float* C,
                          int K, int tile, bool act, float* lAs, float* lBs,
                          int ts)
{
    const int tx = ts & 15;
    const int ty = ts >> 4;
    const int r0 = (tile >> 2) * 64;
    const int c0 = (tile & 3) * 64;
    const int rrA = ts >> 2;
    const int kkA = (ts & 3) * 4;
    float acc[4][4] = {};
    for (int kc = 0; kc < K; kc += 16) {
        if (act) {
            const float4 v = *reinterpret_cast<const float4*>(
                &A[(size_t)(r0 + rrA) * K + kc + kkA]);
            const float vv[4] = {v.x, v.y, v.z, v.w};
#pragma unroll
            for (int m = 0; m < 4; ++m) {
                float xv = vv[m];
                if (AFF) {
                    const int k = kc + kkA + m;
                    xv = fmaxf(fmaf(xv, asc[k], ash[k]), 0.0f);
                }
                lAs[(kkA + m) * 64 + rrA] = xv;
            }
            if (BT) {
                const float4 u = *reinterpret_cast<const float4*>(
                    &Bm[(size_t)(c0 + rrA) * K + kc + kkA]);
                lBs[(kkA + 0) * 64 + rrA] = u.x;
                lBs[(kkA + 1) * 64 + rrA] = u.y;
                lBs[(kkA + 2) * 64 + rrA] = u.z;
                lBs[(kkA + 3) * 64 + rrA] = u.w;
            } else {
                const int kk = ts >> 4;
                const int cc = (ts & 15) * 4;
                const float4 u = *reinterpret_cast<const float4*>(
                    &Bm[(size_t)(kc + kk) * DIMn + c0 + cc]);
                *reinterpret_cast<float4*>(&lBs[kk * 64 + cc]) = u;
            }
        }
        __syncthreads();
        if (act) {
#pragma unroll
            for (int kk = 0; kk < 16; ++kk) {
                const float4 a = *reinterpret_cast<const float4*>(&lAs[kk * 64 + ty * 4]);
                const float4 bv = *reinterpret_cast<const float4*>(&lBs[kk * 64 + tx * 4]);
                const float av[4] = {a.x, a.y, a.z, a.w};
                const float bw[4] = {bv.x, bv.y, bv.z, bv.w};
#pragma unroll
                for (int i = 0; i < 4; ++i)
#pragma unroll
                    for (int j = 0; j < 4; ++j)
                        acc[i][j] = fmaf(av[i], bw[j], acc[i][j]);
            }
        }
        __syncthreads();
    }
    if (act) {
        const int c = c0 + tx * 4;
#pragma unroll
        for (int i = 0; i < 4; ++i) {
            float4 o;
            o.x = acc[i][0] + bias[c + 0];
            o.y = acc[i][1] + bias[c + 1];
            o.z = acc[i][2] + bias[c + 2];
            o.w = acc[i][3] + bias[c + 3];
            *reinterpret_cast<float4*>(&C[(size_t)(r0 + ty * 4 + i) * DIMn + c]) = o;
        }
    }
}

__device__ inline void stage_sync(unsigned* ctr, int t)
{
    __syncthreads();
    if (t == 0) {
        __hip_atomic_fetch_add(ctr, 1u, __ATOMIC_RELEASE, __HIP_MEMORY_SCOPE_AGENT);
        while (__hip_atomic_load(ctr, __ATOMIC_ACQUIRE, __HIP_MEMORY_SCOPE_AGENT)
               < (unsigned)NWORK)
            __builtin_amdgcn_s_sleep(2);
    }
    __syncthreads();
}

// ---------------------------------------------------------------------------
// Fused kernel: blocks 0..3 run FPS (r7 structure, unchanged numerics) and
// publish progress every 256 samples; blocks 4..251 run the h-chain with 8
// stage syncs, then stream gather+topk per query behind FPS progress.
// Each worker serves ONE batch (b = wid&3) -> scalar progress cache.
// All selection numerics bit-identical to the verified r7 kernel.
// ---------------------------------------------------------------------------
__global__ __launch_bounds__(1024, 1) void fused_kernel(
    const float* __restrict__ xyz, const float* __restrict__ points,
    const float* __restrict__ fc1_w, const float* __restrict__ fc1_b,
    const float* __restrict__ conv1_w, const float* __restrict__ conv1_b,
    const float* __restrict__ conv2_w, const float* __restrict__ conv2_b,
    const float* __restrict__ bn1_g, const float* __restrict__ bn1_b,
    const float* __restrict__ bn2_g, const float* __restrict__ bn2_b,
    float* __restrict__ h0, float* __restrict__ A1, float* __restrict__ A2,
    float* __restrict__ pre, int* __restrict__ fidx,
    float* __restrict__ ps, float* __restrict__ pq, float* __restrict__ scv,
    float* __restrict__ newxyz, FusedSync* sync)
{
    __shared__ char smem[81920];                    // fps sx / topk keys / gemm tiles
    __shared__ unsigned long long s_aux[33];        // fps s_wk[2][16] / topk wred+win
    __shared__ int s_nidx[KNEI];
    const int t = threadIdx.x;

    if (blockIdx.x < Bn) {
        // ================= FPS path (r7, + progress publish) =================
#pragma clang fp contract(off)
        float* sx = reinterpret_cast<float*>(smem);                   // [1024*20]
        unsigned long long (*s_wk)[16] =
            reinterpret_cast<unsigned long long (*)[16]>(s_aux);
        const int b = blockIdx.x;
        const int w = t >> 6;
        const int lane = t & 63;
        const float* __restrict__ px = xyz + (size_t)b * Nn * 3;
        float y[16], z[16], dist[16];
#pragma unroll
        for (int a = 0; a < 12; ++a) {
            const float4 v = *reinterpret_cast<const float4*>(&px[48 * t + 4 * a]);
            const float e[4] = {v.x, v.y, v.z, v.w};
#pragma unroll
            for (int c = 0; c < 4; ++c) {
                const int flat = 4 * a + c;
                const int j = flat / 3;
                const int comp = flat - 3 * j;
                if (comp == 0) sx[20 * t + j] = e[c];
                else if (comp == 1) y[j] = e[c];
                else z[j] = e[c];
            }
        }
#pragma unroll
        for (int j = 0; j < 16; ++j) {
            dist[j] = __builtin_huge_valf();
            asm volatile("" : "+v"(y[j]));
            asm volatile("" : "+v"(z[j]));
        }
        float cx = px[0], cy = px[1], cz = px[2];
        if (t == 0) {
            fidx[b * Sn] = 0;
            newxyz[(size_t)b * Sn * 3 + 0] = cx;
            newxyz[(size_t)b * Sn * 3 + 1] = cy;
            newxyz[(size_t)b * Sn * 3 + 2] = cz;
        }
        __syncthreads();
        for (int i = 0; i < Sn - 1; ++i) {
            float bd = -1.0f;
#pragma unroll
            for (int a = 0; a < 4; ++a) {
                const float4 q = *reinterpret_cast<const float4*>(&sx[20 * t + 4 * a]);
                const float xv[4] = {q.x, q.y, q.z, q.w};
#pragma unroll
                for (int c = 0; c < 4; ++c) {
                    const int j = 4 * a + c;
                    const float dx = xv[c] - cx;
                    const float dy = y[j] - cy;
                    const float dz = z[j] - cz;
                    const float d = (dx * dx + dy * dy) + dz * dz;  // no fma
                    const float nd = fminf(dist[j], d);
                    dist[j] = nd;
                    bd = fmaxf(bd, nd);
                }
            }
            unsigned bn = 0;
#pragma unroll
            for (int j = 15; j >= 0; --j)
                if (dist[j] == bd) bn = 0xFFFFFFFFu - (unsigned)(16 * t + j);
            unsigned bdu = __float_as_uint(bd);
            unsigned m = bdu;
            WAVE_UMAX64(m)
            const unsigned bdw = (unsigned)__builtin_amdgcn_readlane((int)m, 63);
            unsigned q2 = (bdu == bdw) ? bn : 0u;
            WAVE_UMAX64(q2)
            const unsigned bnw = (unsigned)__builtin_amdgcn_readlane((int)q2, 63);
            if (lane == 0)
                s_wk[i & 1][w] = ((unsigned long long)bdw << 32) | bnw;
            __syncthreads();
            const unsigned long long kk = (lane < 16) ? s_wk[i & 1][lane] : 0ull;
            unsigned klo = (unsigned)kk;
            unsigned khi = (unsigned)(kk >> 32);
            U64MAX_DPP16(khi, klo, 0x111)
            U64MAX_DPP16(khi, klo, 0x112)
            U64MAX_DPP16(khi, klo, 0x114)
            U64MAX_DPP16(khi, klo, 0x118)
            const unsigned bnf = (unsigned)__builtin_amdgcn_readlane((int)klo, 15);
            const int wu = (int)(0xFFFFFFFFu - bnf);
            cx = px[3 * wu + 0];
            cy = px[3 * wu + 1];
            cz = px[3 * wu + 2];
            if (t == 0) {
                fidx[b * Sn + i + 1] = wu;
                newxyz[(size_t)(b * Sn + i + 1) * 3 + 0] = cx;
                newxyz[(size_t)(b * Sn + i + 1) * 3 + 1] = cy;
                newxyz[(size_t)(b * Sn + i + 1) * 3 + 2] = cz;
                if (((i + 2) & 255) == 0)
                    __hip_atomic_store(&sync->prog[b], (unsigned)(i + 2),
                                       __ATOMIC_RELEASE, __HIP_MEMORY_SCOPE_AGENT);
            }
        }
        return;
    }

    // ======================= worker path =======================
    const int wid = blockIdx.x - Bn;
    const int team = t >> 8;
    const int ts = t & 255;
    float* lAs = reinterpret_cast<float*>(smem) + team * 2048;
    float* lBs = lAs + 1024;
    float* sc1 = scv, *sh1 = scv + 256, *sc2 = scv + 512, *sh2 = scv + 768;

    // S0: fc1 -> h0 (K=32). 4096 tiles over 992 teams, 5 uniform iters.
    for (int it = 0; it < 5; ++it) {
        const int tile = it * (NWORK * 4) + wid * 4 + team;
        gemm_team<false, false>(points, fc1_w, fc1_b, nullptr, nullptr, h0,
                                CINn, tile, tile < 4096, lAs, lBs, ts);
    }
    stage_sync(&sync->stage[0], t);
    // S1: conv1 -> A1 (K=256)
    for (int it = 0; it < 5; ++it) {
        const int tile = it * (NWORK * 4) + wid * 4 + team;
        gemm_team<true, false>(h0, conv1_w, conv1_b, nullptr, nullptr, A1,
                               DIMn, tile, tile < 4096, lAs, lBs, ts);
    }
    stage_sync(&sync->stage[1], t);
    // S2: BN1 stats (slabs of 256 rows)
    for (int sb = wid; sb < 256; sb += NWORK) {
        if (t < DIMn) {
            float s = 0.0f, q = 0.0f;
            const size_t r0 = (size_t)sb * 256;
            for (int r = 0; r < 256; ++r) {
                const float v = A1[(r0 + r) * DIMn + t];
                s += v;
                q = fmaf(v, v, q);
            }
            ps[sb * DIMn + t] = s;
            pq[sb * DIMn + t] = q;
        }
    }
    stage_sync(&sync->stage[2], t);
    // S3: BN1 finalize (block 0)
    if (wid == 0 && t < DIMn) {
        float s = 0.0f, q = 0.0f;
        for (int i = 0; i < 256; ++i) { s += ps[i * DIMn + t]; q += pq[i * DIMn + t]; }
        const float invN = 1.0f / MROWS;
        const float mean = s * invN;
        const float var = q * invN - mean * mean;
        const float r = 1.0f / sqrtf(var + BNEPS);
        const float scale = bn1_g[t] * r;
        sc1[t] = scale;
        sh1[t] = bn1_b[t] - mean * scale;
    }
    stage_sync(&sync->stage[3], t);
    // S4: conv2 -> A2 (BN1+relu fused into A-load)
    for (int it = 0; it < 5; ++it) {
        const int tile = it * (NWORK * 4) + wid * 4 + team;
        gemm_team<true, true>(A1, conv2_w, conv2_b, sc1, sh1, A2,
                              DIMn, tile, tile < 4096, lAs, lBs, ts);
    }
    stage_sync(&sync->stage[4], t);
    // S5: BN2 stats
    for (int sb = wid; sb < 256; sb += NWORK) {
        if (t < DIMn) {
            float s = 0.0f, q = 0.0f;
            const size_t r0 = (size_t)sb * 256;
            for (int r = 0; r < 256; ++r) {
                const float v = A2[(r0 + r) * DIMn + t];
                s += v;
                q = fmaf(v, v, q);
            }
            ps[sb * DIMn + t] = s;
            pq[sb * DIMn + t] = q;
        }
    }
    stage_sync(&sync->stage[5], t);
    // S6: BN2 finalize
    if (wid == 0 && t < DIMn) {
        float s = 0.0f, q = 0.0f;
        for (int i = 0; i < 256; ++i) { s += ps[i * DIMn + t]; q += pq[i * DIMn + t]; }
        const float invN = 1.0f / MROWS;
        const float mean = s * invN;
        const float var = q * invN - mean * mean;
        const float r = 1.0f / sqrtf(var + BNEPS);
        const float scale = bn2_g[t] * r;
        sc2[t] = scale;
        sh2[t] = bn2_b[t] - mean * scale;
    }
    stage_sync(&sync->stage[6], t);
    // S7: h_final = h0 + relu(BN2(A2)) -> A2 (h0 preserved for points_ori)
    for (size_t idx = (size_t)wid * 1024 + t; idx < (size_t)MROWS * DIMn / 4;
         idx += (size_t)NWORK * 1024) {
        const int c4 = (int)(idx & 63);
        const float4 hv = reinterpret_cast<const float4*>(h0)[idx];
        float4 av = reinterpret_cast<float4*>(A2)[idx];
        const float4 s4 = reinterpret_cast<const float4*>(sc2)[c4];
        const float4 b4 = reinterpret_cast<const float4*>(sh2)[c4];
        av.x = hv.x + fmaxf(fmaf(av.x, s4.x, b4.x), 0.0f);
        av.y = hv.y + fmaxf(fmaf(av.y, s4.y, b4.y), 0.0f);
        av.z = hv.z + fmaxf(fmaf(av.z, s4.z, b4.z), 0.0f);
        av.w = hv.w + fmaxf(fmaf(av.w, s4.w, b4.w), 0.0f);
        reinterpret_cast<float4*>(A2)[idx] = av;
    }
    stage_sync(&sync->stage[7], t);

    // S8: per-query gather + 16-NN + maxpool, streamed behind FPS progress.
    {
#pragma clang fp contract(off)
        unsigned* s_key = reinterpret_cast<unsigned*>(smem);          // 64 KB
        const int b = wid & 3;
        const int w = t >> 6;
        const int lane = t & 63;
        const float* px = xyz + (size_t)b * Nn * 3;
        unsigned cprog = 0;
        for (int q = wid; q < SROWS; q += NWORK) {
            const int s = q >> 2;
            if (t == 0 && cprog < (unsigned)(s + 1)) {
                unsigned p;
                do {
                    p = __hip_atomic_load(&sync->prog[b], __ATOMIC_ACQUIRE,
                                          __HIP_MEMORY_SCOPE_AGENT);
                    if (p < (unsigned)(s + 1)) __builtin_amdgcn_s_sleep(8);
                } while (p < (unsigned)(s + 1));
                cprog = p;
            }
            __syncthreads();
            const int bs = b * Sn + s;
            const float qx = newxyz[(size_t)bs * 3 + 0];
            const float qy = newxyz[(size_t)bs * 3 + 1];
            const float qz = newxyz[(size_t)bs * 3 + 2];
            const float qq = (qx * qx + qy * qy) + qz * qz;
            unsigned long long mkey = ~0ull;
#pragma unroll 4
            for (int u = 0; u < 16; ++u) {
                const int n = t + (u << 10);
                const float bx = px[n * 3 + 0];
                const float by = px[n * 3 + 1];
                const float bz = px[n * 3 + 2];
                const float bb2 = (bx * bx + by * by) + bz * bz;
                const float ab = (qx * bx + qy * by) + qz * bz;
                const float d = (qq + bb2) - 2.0f * ab;   // exact reference formula
                unsigned u32 = __float_as_uint(d);
                u32 = ((int)u32 < 0) ? ~u32 : (u32 | 0x80000000u);
                s_key[n] = u32;
                const unsigned long long k =
                    ((unsigned long long)u32 << 32) | (unsigned)n;
                mkey = (k < mkey) ? k : mkey;
            }
            __syncthreads();
            for (int r = 0; r < KNEI; ++r) {
                unsigned long long k = mkey;
#pragma unroll
                for (int off = 32; off > 0; off >>= 1) {
                    const unsigned long long o = __shfl_xor(k, off);
                    k = (o < k) ? o : k;
                }
                if (lane == 0) s_aux[w] = k;
                __syncthreads();
                if (w == 0) {
                    unsigned long long kk = (lane < 16) ? s_aux[lane] : ~0ull;
#pragma unroll
                    for (int off = 8; off > 0; off >>= 1) {
                        const unsigned long long o = __shfl_xor(kk, off);
                        kk = (o < kk) ? o : kk;
                    }
                    if (lane == 0) {
                        s_aux[32] = kk;
                        s_nidx[r] = (int)(unsigned)(kk & 0xFFFFFFFFull);
                    }
                }
                __syncthreads();
                const unsigned long long wk = s_aux[32];
                if (wk == mkey) {
                    const int wn = (int)(unsigned)(wk & 0xFFFFFFFFull);
                    s_key[wn] = 0xFFFFFFFFu;
                    mkey = ~0ull;
#pragma unroll 4
                    for (int u = 0; u < 16; ++u) {
                        const int n = t + (u << 10);
                        const unsigned long long kk2 =
                            ((unsigned long long)s_key[n] << 32) | (unsigned)n;
                        mkey = (kk2 < mkey) ? kk2 : mkey;
                    }
                }
            }
            __syncthreads();
            if (t < DIMn) {
                const int fid = fidx[bs];
                const float po = h0[((size_t)b * Nn + fid) * DIMn + t];
                float m = -__builtin_huge_valf();
#pragma unroll
                for (int r = 0; r < KNEI; ++r) {
                    const int n = s_nidx[r];
                    m = fmaxf(m, A2[((size_t)b * Nn + n) * DIMn + t]);
                }
                pre[(size_t)bs * DIMn + t] = po + m;
            }
            __syncthreads();
        }
    }
}

// ---------------------------------------------------------------------------
// final BN (serial tail, ~60us): stats, finalize, apply
// ---------------------------------------------------------------------------
__global__ __launch_bounds__(256) void stats_partial(const float* __restrict__ X,
                                                     int rowsPerBlk,
                                                     float* __restrict__ ps,
                                                     float* __restrict__ pq)
{
    const int c = threadIdx.x;
    const size_t r0 = (size_t)blockIdx.x * rowsPerBlk;
    float s = 0.0f, q = 0.0f;
    for (int r = 0; r < rowsPerBlk; ++r) {
        const float v = X[(r0 + r) * DIMn + c];
        s += v;
        q = fmaf(v, v, q);
    }
    ps[blockIdx.x * DIMn + c] = s;
    pq[blockIdx.x * DIMn + c] = q;
}

__global__ __launch_bounds__(256) void bn_finalize(const float* __restrict__ ps,
                                                   const float* __restrict__ pq,
                                                   int nblk, float invN,
                                                   const float* __restrict__ g,
                                                   const float* __restrict__ bb,
                                                   float* __restrict__ sc,
                                                   float* __restrict__ sh)
{
    const int c = threadIdx.x;
    float s = 0.0f, q = 0.0f;
    for (int i = 0; i < nblk; ++i) {
        s += ps[i * DIMn + c];
        q += pq[i * DIMn + c];
    }
    const float mean = s * invN;
    const float var = q * invN - mean * mean;
    const float r = 1.0f / sqrtf(var + BNEPS);
    const float scale = g[c] * r;
    sc[c] = scale;
    sh[c] = bb[c] - mean * scale;
}

__global__ __launch_bounds__(256) void apply_bn_kernel(const float* __restrict__ pre,
                                                       const float* __restrict__ sc,
                                                       const float* __restrict__ sh,
                                                       float* __restrict__ out)
{
    const size_t i = (size_t)blockIdx.x * 256 + threadIdx.x;
    const int c4 = (int)(i & 63);
    const float4 v = reinterpret_cast<const float4*>(pre)[i];
    const float4 s4 = reinterpret_cast<const float4*>(sc)[c4];
    const float4 b4 = reinterpret_cast<const float4*>(sh)[c4];
    float4 o;
    o.x = fmaf(v.x, s4.x, b4.x);
    o.y = fmaf(v.y, s4.y, b4.y);
    o.z = fmaf(v.z, s4.z, b4.z);
    o.w = fmaf(v.w, s4.w, b4.w);
    reinterpret_cast<float4*>(out)[i] = o;
}

// ---------------------------------------------------------------------------
// Launch. ws layout: h0 0-64Mi | A1 64-128Mi | A2 128-192Mi | pre 192-200Mi |
// fidx 200Mi | ps/pq/scv/sc3/sh3 201Mi | FusedSync 203Mi.
// ---------------------------------------------------------------------------
extern "C" void kernel_launch(void* const* d_in, const int* in_sizes, int n_in,
                              void* d_out, int out_size, void* d_ws, size_t ws_size,
                              hipStream_t stream)
{
    (void)in_sizes; (void)n_in; (void)out_size; (void)ws_size;
    const float* xyz     = (const float*)d_in[0];
    const float* points  = (const float*)d_in[1];
    const float* fc1_w   = (const float*)d_in[2];
    const float* fc1_b   = (const float*)d_in[3];
    const float* conv1_w = (const float*)d_in[4];
    const float* conv1_b = (const float*)d_in[5];
    const float* conv2_w = (const float*)d_in[6];
    const float* conv2_b = (const float*)d_in[7];
    const float* bn1_g   = (const float*)d_in[8];
    const float* bn1_b   = (const float*)d_in[9];
    const float* bn2_g   = (const float*)d_in[10];
    const float* bn2_b   = (const float*)d_in[11];
    const float* bn_g    = (const float*)d_in[12];
    const float* bn_b    = (const float*)d_in[13];

    float* out = (float*)d_out;
    float* newxyz = out;                       // [4,2048,3]
    float* outpts = out + (size_t)Bn * Sn * 3; // [4,2048,256]

    char* w = (char*)d_ws;
    float* h0   = (float*)(w);
    float* A1   = (float*)(w + (64ull << 20));
    float* A2   = (float*)(w + (128ull << 20));
    float* pre  = (float*)(w + (192ull << 20));
    int*   fidx = (int*)  (w + (200ull << 20));
    float* ps   = (float*)(w + (201ull << 20));
    float* pq   = ps + 256 * 256;
    float* scv  = pq + 256 * 256;              // sc1,sh1,sc2,sh2 [4][256]
    float* sc3  = scv + 1024;
    float* sh3  = sc3 + 256;
    FusedSync* sync = (FusedSync*)(w + (203ull << 20));

    fps_zero_kernel<<<1, 64, 0, stream>>>((unsigned*)sync);
    fused_kernel<<<NBLK, 1024, 0, stream>>>(
        xyz, points, fc1_w, fc1_b, conv1_w, conv1_b, conv2_w, conv2_b,
        bn1_g, bn1_b, bn2_g, bn2_b, h0, A1, A2, pre, fidx, ps, pq, scv,
        newxyz, sync);
    stats_partial<<<64, 256, 0, stream>>>(pre, SROWS / 64, ps, pq);
    bn_finalize<<<1, 256, 0, stream>>>(ps, pq, 64, 1.0f / SROWS, bn_g, bn_b, sc3, sh3);
    apply_bn_kernel<<<(SROWS * DIMn / 4) / 256, 256, 0, stream>>>(pre, sc3, sh3, outpts);
}